// Round 7
// baseline (4231.319 us; speedup 1.0000x reference)
//
#include <hip/hip_runtime.h>
#include <math.h>

#define LL 256
#define BB 256
#define HH 256
#define CC 16
#define YY 32
#define HC (HH*CC)     // 4096
#define NSTEP (LL-1)   // 255
#define NBG 32         // batch groups
#define BGB 8          // batches per group
#define HCH 32         // h per chunk (=> 512 W2 cols per block)
#define TPB 1024
#define NJS 8          // phase-B j-split slices
#define AJS 16         // phase-A j-splits (16 j each)

// fast tanh: 1 - 2/(e^{2x}+1). Saturates correctly, no branches, ~7 VALU.
__device__ __forceinline__ float fast_tanh(float x) {
    float e = __expf(2.0f * x);
    return 1.0f - 2.0f / (e + 1.0f);
}

// coherence-point (device-coherent) access: bypasses the non-coherent
// per-XCD L2s. Used ONLY for the cross-block z exchange.
__device__ __forceinline__ float2 ld_coh2(const float* p) {
    union { unsigned long long u; float2 f; } cv;
    cv.u = __hip_atomic_load((const unsigned long long*)p,
                             __ATOMIC_RELAXED, __HIP_MEMORY_SCOPE_AGENT);
    return cv.f;
}
__device__ __forceinline__ void st_coh(float* p, float v) {
    __hip_atomic_store(p, v, __ATOMIC_RELAXED, __HIP_MEMORY_SCOPE_AGENT);
}

// 8-way sibling barrier, monotonic per-group counter (no reset).
// __syncthreads() drains vmem (vmcnt(0) before s_barrier) so all coherent
// stores are visible before the arrival add. 32 groups on 32 distinct lines.
__device__ __forceinline__ void bg_barrier(unsigned* cnt, unsigned target) {
    __syncthreads();
    if (threadIdx.x == 0) {
        __hip_atomic_fetch_add(cnt, 1u, __ATOMIC_RELAXED, __HIP_MEMORY_SCOPE_AGENT);
        while (__hip_atomic_load(cnt, __ATOMIC_RELAXED, __HIP_MEMORY_SCOPE_AGENT) < target)
            __builtin_amdgcn_s_sleep(2);
    }
    __syncthreads();
}

// ---------------------------------------------------------------------------
// persistent scan: 256 blocks = 32 bg x 8 hc, 1024 threads (16 waves/CU).
// block (bg,hc): batches b0..b0+7; computes FULL hid (256) for its batches
// (redundant across the 8 hc siblings -> no hid exchange, ONE barrier/step),
// then its own 512 W2 columns for phase B. W1+W2 stream from warm L2.
// ---------------------------------------------------------------------------
__global__ void __launch_bounds__(TPB)
k_scan(const float* __restrict__ us, const float* __restrict__ W1,
       const float* __restrict__ b1, const float* __restrict__ W2,
       const float* __restrict__ b2, float* __restrict__ zs,
       unsigned* __restrict__ barG) {
    __shared__ float smem[NJS * BGB * 512 + 2048 + 2048 + 512 + 128 + 256];
    float* psum  = smem;                         // [8][8][512]  128 KB (phase B)
    float* pa    = smem;                         // alias [16][2048] (phase A)
    float* z_loc = smem + NJS * BGB * 512;       // [8][256]     8 KB
    float* hidT  = z_loc + BGB * HH;             // [256][8]     8 KB
    float* b2s   = hidT + HH * BGB;              // [512]
    float* dvs   = b2s + 512;                    // [8][16]
    float* b1s   = dvs + 128;                    // [256]

    const int bg = blockIdx.x >> 3;
    const int hc = blockIdx.x & 7;
    const int t  = threadIdx.x;
    const int b0 = bg * BGB;
    const int n0 = hc * HCH * CC;                // = hc*512

    for (int i = t; i < 512; i += TPB) b2s[i] = b2[n0 + i];
    for (int i = t; i < HH; i += TPB) b1s[i] = b1[i];
    __syncthreads();

    unsigned* cnt = barG + (size_t)bg * 64;      // 256-B line per group

    // staging indices (8-byte coherent loads)
    const int sb  = t >> 7;                      // 0..7
    const int sj2 = (t & 127) << 1;              // 0,2,..,254
    // phase-A indices: thread = (ajs: 16 j's) x (hq: h-quad)
    const int hq  = t & 63;                      // h = hq*4 + i
    const int ajs = t >> 6;                      // 0..15
    // phase-B indices: thread (jsp -> 32 j's, 4 cols at ct)
    const int jsp = t >> 7;                      // 0..7
    const int ct  = (t & 127) << 2;              // 0..508
    // dz indices
    const int col = t & 511;
    const int bh  = (t >> 9) << 2;               // 0 or 4

    for (int k = 0; k < NSTEP; k++) {
        const size_t zk = (size_t)k * (BB * HH);

        // ---- stage z_loc (coherent 8B, coalesced) + dvs ----
        {
            float2 v = ld_coh2(&zs[zk + (size_t)(b0 + sb) * HH + sj2]);
            *(float2*)&z_loc[sb * HH + sj2] = v;
        }
        if (t < BGB * CC) {
            int b = t >> 4, c = t & 15;
            int kk = (k < 1) ? 1 : k;
            float v = 1.0f;                      // c==0: ts diff == 1
            if (c > 0)
                v = us[((size_t)kk * BB + b0 + b) * (CC - 1) + c - 1]
                  - us[((size_t)(kk - 1) * BB + b0 + b) * (CC - 1) + c - 1];
            dvs[b * CC + c] = v;
        }
        __syncthreads();

        // ---- phase A: FULL hid(8x256) = z(8x256) @ W1(256x256), j-split 16 ----
        {
            float4 accA[BGB];
            #pragma unroll
            for (int b = 0; b < BGB; b++) accA[b] = make_float4(0.f, 0.f, 0.f, 0.f);
            const float* w1p = &W1[(size_t)(ajs * 16) * HH + hq * 4];
            #pragma unroll 4
            for (int j = 0; j < 16; j++) {
                float4 w = *(const float4*)&w1p[(size_t)j * HH];   // coalesced
                #pragma unroll
                for (int b = 0; b < BGB; b++) {
                    float zv = z_loc[b * HH + ajs * 16 + j];       // broadcast
                    accA[b].x += zv * w.x; accA[b].y += zv * w.y;
                    accA[b].z += zv * w.z; accA[b].w += zv * w.w;
                }
            }
            #pragma unroll
            for (int b = 0; b < BGB; b++)
                *(float4*)&pa[ajs * 2048 + b * 256 + hq * 4] = accA[b];
        }
        __syncthreads();
        {   // reduce 16 j-split partials -> relu -> hidT[h][b]; 2 outputs/thread
            #pragma unroll
            for (int rep = 0; rep < 2; rep++) {
                int o = t + rep * 1024;          // o = b*256 + h
                float s = b1s[o & 255];
                #pragma unroll
                for (int q = 0; q < AJS; q++) s += pa[q * 2048 + o]; // stride-1
                hidT[(o & 255) * BGB + (o >> 8)] = fmaxf(s, 0.f);
            }
        }
        __syncthreads();

        // ---- phase B: hid(8x256) @ W2-slice(256x512); thread: 32 j x 8 b x 4 c ----
        {
            float4 acc[BGB];
            #pragma unroll
            for (int b = 0; b < BGB; b++) acc[b] = make_float4(0.f, 0.f, 0.f, 0.f);
            const int jb = jsp * 32;
            const float* w2p = &W2[(size_t)jb * HC + n0 + ct];
            #pragma unroll 4
            for (int j = 0; j < 32; j++) {
                float4 hA = *(const float4*)&hidT[(jb + j) * BGB];     // bcast
                float4 hB = *(const float4*)&hidT[(jb + j) * BGB + 4]; // bcast
                float4 w  = *(const float4*)&w2p[(size_t)j * HC];      // 16B/lane
                acc[0].x += hA.x * w.x; acc[0].y += hA.x * w.y;
                acc[0].z += hA.x * w.z; acc[0].w += hA.x * w.w;
                acc[1].x += hA.y * w.x; acc[1].y += hA.y * w.y;
                acc[1].z += hA.y * w.z; acc[1].w += hA.y * w.w;
                acc[2].x += hA.z * w.x; acc[2].y += hA.z * w.y;
                acc[2].z += hA.z * w.z; acc[2].w += hA.z * w.w;
                acc[3].x += hA.w * w.x; acc[3].y += hA.w * w.y;
                acc[3].z += hA.w * w.z; acc[3].w += hA.w * w.w;
                acc[4].x += hB.x * w.x; acc[4].y += hB.x * w.y;
                acc[4].z += hB.x * w.z; acc[4].w += hB.x * w.w;
                acc[5].x += hB.y * w.x; acc[5].y += hB.y * w.y;
                acc[5].z += hB.y * w.z; acc[5].w += hB.y * w.w;
                acc[6].x += hB.z * w.x; acc[6].y += hB.z * w.y;
                acc[6].z += hB.z * w.z; acc[6].w += hB.z * w.w;
                acc[7].x += hB.w * w.x; acc[7].y += hB.w * w.y;
                acc[7].z += hB.w * w.z; acc[7].w += hB.w * w.w;
            }
            #pragma unroll
            for (int b = 0; b < BGB; b++)
                *(float4*)&psum[((jsp * BGB + b) << 9) + ct] = acc[b];
        }
        __syncthreads();

        // ---- dz + z update: lane owns col; 16-lane shfl c-reduction ----
        {
            #pragma unroll
            for (int q = 0; q < 4; q++) {
                int b = bh + q;
                float g = b2s[col];
                #pragma unroll
                for (int s = 0; s < NJS; s++)
                    g += psum[((s * BGB + b) << 9) + col];   // stride-1
                float v = fast_tanh(g) * dvs[b * CC + (col & 15)];
                v += __shfl_xor(v, 1);
                v += __shfl_xor(v, 2);
                v += __shfl_xor(v, 4);
                v += __shfl_xor(v, 8);
                if ((col & 15) == 0) {
                    int hl = col >> 4;
                    int h = hc * HCH + hl;
                    st_coh(&zs[zk + (size_t)(BB * HH) + (size_t)(b0 + b) * HH + h],
                           z_loc[b * HH + h] + v);           // dt == 1
                }
            }
        }
        bg_barrier(cnt, 8u * (unsigned)(k + 1));             // z[k+1] complete
    }
}

// ---------------------------------------------------------------------------
// out = tanh(z_seq @ dW1 + db1) @ dW2 + db2   (zs natural layout [l*B+b][H])
// grid: L*B/16 = 4096 blocks, 256 threads
// ---------------------------------------------------------------------------
__global__ void k_out(const float* __restrict__ zseq, const float* __restrict__ dW1,
                      const float* __restrict__ db1, const float* __restrict__ dW2,
                      const float* __restrict__ db2, float* __restrict__ out) {
    __shared__ float zt[16][HH];       // 16 KB
    __shared__ float act[16][2 * HH];  // 32 KB
    int r0 = blockIdx.x * 16;
    int t  = threadIdx.x;
    {
        const float4* src = (const float4*)(zseq + (size_t)r0 * HH);
        float4* dst = (float4*)&zt[0][0];
        for (int i = t; i < 1024; i += 256) dst[i] = src[i];
    }
    __syncthreads();
    {   // phase 1: act = tanh(z @ dW1 + db1), 512 cols
        int c0  = (t & 127) * 4;
        int rr0 = (t >> 7) * 8;
        float a[8][4];
        #pragma unroll
        for (int i = 0; i < 8; i++)
            #pragma unroll
            for (int q = 0; q < 4; q++) a[i][q] = 0.f;
        for (int j = 0; j < HH; j++) {
            float4 w = *(const float4*)&dW1[(size_t)j * 2 * HH + c0];
            #pragma unroll
            for (int i = 0; i < 8; i++) {
                float zv = zt[rr0 + i][j];
                a[i][0] += zv * w.x; a[i][1] += zv * w.y;
                a[i][2] += zv * w.z; a[i][3] += zv * w.w;
            }
        }
        float4 bias = *(const float4*)&db1[c0];
        #pragma unroll
        for (int i = 0; i < 8; i++) {
            act[rr0 + i][c0 + 0] = fast_tanh(a[i][0] + bias.x);
            act[rr0 + i][c0 + 1] = fast_tanh(a[i][1] + bias.y);
            act[rr0 + i][c0 + 2] = fast_tanh(a[i][2] + bias.z);
            act[rr0 + i][c0 + 3] = fast_tanh(a[i][3] + bias.w);
        }
    }
    __syncthreads();
    {   // phase 2: out = act @ dW2 + db2
        int rl = t >> 4;
        int y2 = t & 15;
        float o0 = 0.f, o1 = 0.f;
        #pragma unroll 4
        for (int j = 0; j < 2 * HH; j++) {
            float av = act[rl][j];
            float2 w = *(const float2*)&dW2[(size_t)j * YY + y2 * 2];
            o0 += av * w.x; o1 += av * w.y;
        }
        float2 bias = *(const float2*)&db2[y2 * 2];
        out[(size_t)(r0 + rl) * YY + y2 * 2]     = o0 + bias.x;
        out[(size_t)(r0 + rl) * YY + y2 * 2 + 1] = o1 + bias.y;
    }
}

// ---------------------------------------------------------------------------
extern "C" void kernel_launch(void* const* d_in, const int* in_sizes, int n_in,
                              void* d_out, int out_size, void* d_ws, size_t ws_size,
                              hipStream_t stream) {
    const float* us  = (const float*)d_in[1];
    const float* h0  = (const float*)d_in[2];
    const float* W1  = (const float*)d_in[3];
    const float* b1  = (const float*)d_in[4];
    const float* W2  = (const float*)d_in[5];
    const float* b2  = (const float*)d_in[6];
    const float* dW1 = (const float*)d_in[7];
    const float* db1 = (const float*)d_in[8];
    const float* dW2 = (const float*)d_in[9];
    const float* db2 = (const float*)d_in[10];
    float* out = (float*)d_out;

    float* zs   = (float*)d_ws;                          // L*B*H = 64 MB, [l*B+b][h]
    unsigned* barG = (unsigned*)(zs + (size_t)LL * BB * HH); // 32 x 256 B = 8 KB

    hipMemcpyAsync(zs, h0, (size_t)BB * HH * sizeof(float),
                   hipMemcpyDeviceToDevice, stream);
    hipMemsetAsync(barG, 0, NBG * 64 * sizeof(unsigned), stream);

    k_scan<<<NBG * 8, TPB, 0, stream>>>(us, W1, b1, W2, b2, zs, barG);
    k_out<<<LL * BB / 16, 256, 0, stream>>>(zs, dW1, db1, dW2, db2, out);
}